// Round 2
// baseline (567.627 us; speedup 1.0000x reference)
//
#include <hip/hip_runtime.h>

#define NN 50000
#define NE 1600000
#define SCAN_T 1024
#define CHUNK 49  // ceil(NN / SCAN_T)

// ---------------- workspace layout (floats) ----------------
// er[2*NE]  : float2 records {src_bits, dinv[src]*ew} sorted by dst   (12.8 MB)
// deg[NN]   : float  sum of incoming edge weights (memset 0)
// cnt[NN]   : u32    incoming edge count          (memset 0, contiguous w/ deg)
// rowptr[NN+1], pos[NN], dinv[NN]
// Mz[1024], Mh[1024], cz[32], ch[32]
// total ~= 13.8 MB

// Fold Wz@Lzw_top -> Mz (cz = bz@Lzw_top + Lzb); same for h. One block, 1024 thr.
__global__ void k_prep(const float* __restrict__ Wz, const float* __restrict__ Lzw,
                       const float* __restrict__ bz, const float* __restrict__ Lzb,
                       const float* __restrict__ Wh, const float* __restrict__ Lhw,
                       const float* __restrict__ bh, const float* __restrict__ Lhb,
                       float* __restrict__ Mz, float* __restrict__ Mh,
                       float* __restrict__ cz, float* __restrict__ ch) {
    int t = threadIdx.x;
    int i = t >> 5, j = t & 31;
    float sz = 0.f, sh = 0.f;
#pragma unroll
    for (int k = 0; k < 32; ++k) {
        sz += Wz[i * 32 + k] * Lzw[k * 32 + j];
        sh += Wh[i * 32 + k] * Lhw[k * 32 + j];
    }
    Mz[i * 32 + j] = sz;
    Mh[i * 32 + j] = sh;
    if (t < 32) {
        float az = Lzb[t], ah = Lhb[t];
        for (int k = 0; k < 32; ++k) {
            az += bz[k] * Lzw[k * 32 + t];
            ah += bh[k] * Lhw[k * 32 + t];
        }
        cz[t] = az;
        ch[t] = ah;
    }
}

// deg[dst] += ew ; cnt[dst] += 1   (3.2M atomics on 400KB, L2-resident)
__global__ void k_count(const int* __restrict__ ei, const float* __restrict__ ew,
                        float* __restrict__ deg, unsigned* __restrict__ cnt) {
    int e = blockIdx.x * blockDim.x + threadIdx.x;
    if (e < NE) {
        int d = ei[NE + e];
        atomicAdd(&deg[d], ew[e]);
        atomicAdd(&cnt[d], 1u);
    }
}

// Single-block exclusive scan of cnt -> rowptr & pos; fused dinv = rsqrt(deg+1).
__global__ __launch_bounds__(SCAN_T) void k_scan(
        const unsigned* __restrict__ cnt, const float* __restrict__ deg,
        unsigned* __restrict__ rowptr, unsigned* __restrict__ pos,
        float* __restrict__ dinv) {
    __shared__ unsigned part[SCAN_T];
    int t = threadIdx.x;
    int lo = t * CHUNK;
    int hi = lo + CHUNK; if (hi > NN) hi = NN; if (lo > NN) lo = NN;
    unsigned s = 0;
    for (int n = lo; n < hi; ++n) s += cnt[n];
    part[t] = s;
    __syncthreads();
    for (int off = 1; off < SCAN_T; off <<= 1) {  // Hillis-Steele inclusive
        unsigned v = (t >= off) ? part[t - off] : 0u;
        __syncthreads();
        part[t] += v;
        __syncthreads();
    }
    unsigned base = (t > 0) ? part[t - 1] : 0u;
    for (int n = lo; n < hi; ++n) {
        rowptr[n] = base;
        pos[n] = base;
        base += cnt[n];
        dinv[n] = rsqrtf(deg[n] + 1.0f);  // +1 = self-loop weight; always > 0
    }
    if (t == SCAN_T - 1) rowptr[NN] = base;  // == NE
}

// Place {src, dinv[src]*ew} record into dst's CSR slot. 1.6M int atomics.
__global__ void k_scatter(const int* __restrict__ ei, const float* __restrict__ ew,
                          const float* __restrict__ dinv, unsigned* __restrict__ pos,
                          float2* __restrict__ er) {
    int e = blockIdx.x * blockDim.x + threadIdx.x;
    if (e < NE) {
        int s = ei[e];
        int d = ei[NE + e];
        float v = dinv[s] * ew[e];
        unsigned idx = atomicAdd(&pos[d], 1u);
        er[idx] = make_float2(__int_as_float(s), v);
    }
}

// Owner-computes gather + full dense epilogue. 32 lanes = 1 node, 8 nodes/block.
// NN/8 = 6250 blocks exactly (no remainder -> uniform __syncthreads).
__global__ __launch_bounds__(256) void k_fused(
        const float2* __restrict__ er, const unsigned* __restrict__ rowptr,
        const float* __restrict__ dinv, const float* __restrict__ x,
        const float* __restrict__ Mz, const float* __restrict__ Mh,
        const float* __restrict__ cz, const float* __restrict__ ch,
        const float* __restrict__ Wout, const float* __restrict__ bout,
        float* __restrict__ out) {
    __shared__ float sMz[1024], sMh[1024], sW[512], scz[32], sch[32], sb[16];
    __shared__ float sA[8][32];
    int tid = threadIdx.x;
    for (int i = tid; i < 1024; i += 256) { sMz[i] = Mz[i]; sMh[i] = Mh[i]; }
    for (int i = tid; i < 512; i += 256) sW[i] = Wout[i];
    if (tid < 32) { scz[tid] = cz[tid]; sch[tid] = ch[tid]; }
    if (tid < 16) sb[tid] = bout[tid];
    __syncthreads();

    int g = tid >> 5, f = tid & 31;
    int n = blockIdx.x * 8 + g;

    // gather: t = sum over incoming edges of val * x[src][f]
    unsigned beg = rowptr[n], end = rowptr[n + 1];
    float t = 0.f;
    for (unsigned i = beg; i < end; ++i) {
        float2 r = er[i];                      // broadcast across the 32 lanes
        int s = __float_as_int(r.x);
        t += r.y * x[s * 32 + f];              // coalesced 128B row gather
    }
    float dn = dinv[n];
    float a = dn * (t + dn * x[n * 32 + f]);   // self-loop folded in
    sA[g][f] = a;
    __syncthreads();

    // gates: z = sigmoid(a@Mz + cz), h~ = tanh(a@Mh + ch), H = (1-z)*h~, relu
    float z = scz[f], gh = sch[f];
#pragma unroll
    for (int k = 0; k < 32; ++k) {
        float ak = sA[g][k];                   // broadcast read
        z += ak * sMz[k * 32 + f];
        gh += ak * sMh[k * 32 + f];
    }
    z = 1.0f / (1.0f + expf(-z));
    gh = tanhf(gh);
    float hv = (1.0f - z) * gh;
    hv = hv > 0.f ? hv : 0.f;
    __syncthreads();                           // all lanes done reading sA as 'a'
    sA[g][f] = hv;
    __syncthreads();

    // logits + softmax: lanes 0..15 each own one class
    if (f < 16) {
        float l = sb[f];
#pragma unroll
        for (int j = 0; j < 32; ++j) l += sA[g][j] * sW[j * 16 + f];
        float mx = l;
#pragma unroll
        for (int w = 8; w >= 1; w >>= 1) mx = fmaxf(mx, __shfl_xor(mx, w, 16));
        float p = expf(l - mx);
        float sum = p;
#pragma unroll
        for (int w = 8; w >= 1; w >>= 1) sum += __shfl_xor(sum, w, 16);
        out[n * 16 + f] = p / sum;
    }
}

extern "C" void kernel_launch(void* const* d_in, const int* in_sizes, int n_in,
                              void* d_out, int out_size, void* d_ws, size_t ws_size,
                              hipStream_t stream) {
    const float* x    = (const float*)d_in[0];
    const int*   ei   = (const int*)d_in[1];
    const float* ew   = (const float*)d_in[2];
    const float* Wz   = (const float*)d_in[3];
    const float* bz   = (const float*)d_in[4];
    // d_in[5..6] (Wr,br) dead: R gate multiplies H0=0. d_in[11..12] (Lr) dead too.
    const float* Wh   = (const float*)d_in[7];
    const float* bh   = (const float*)d_in[8];
    const float* Lzw  = (const float*)d_in[9];
    const float* Lzb  = (const float*)d_in[10];
    const float* Lhw  = (const float*)d_in[13];
    const float* Lhb  = (const float*)d_in[14];
    const float* Wout = (const float*)d_in[15];
    const float* bout = (const float*)d_in[16];
    float* out = (float*)d_out;

    float* ws = (float*)d_ws;
    float2*   er     = (float2*)ws;                       // 2*NE floats
    float*    deg    = ws + 2 * (size_t)NE;               // NN
    unsigned* cnt    = (unsigned*)(deg + NN);             // NN (contiguous w/ deg)
    unsigned* rowptr = cnt + NN;                          // NN+1
    unsigned* pos    = rowptr + NN + 1;                   // NN
    float*    dinv   = (float*)(pos + NN);                // NN
    float*    Mz     = dinv + NN;                         // 1024
    float*    Mh     = Mz + 1024;                         // 1024
    float*    cz     = Mh + 1024;                         // 32
    float*    ch     = cz + 32;                           // 32

    // zero deg+cnt (workspace is poisoned; these are accumulated into)
    hipMemsetAsync(deg, 0, 2 * NN * sizeof(float), stream);

    k_prep<<<1, 1024, 0, stream>>>(Wz, Lzw, bz, Lzb, Wh, Lhw, bh, Lhb, Mz, Mh, cz, ch);
    k_count<<<(NE + 255) / 256, 256, 0, stream>>>(ei, ew, deg, cnt);
    k_scan<<<1, SCAN_T, 0, stream>>>(cnt, deg, rowptr, pos, dinv);
    k_scatter<<<(NE + 255) / 256, 256, 0, stream>>>(ei, ew, dinv, pos, er);
    k_fused<<<NN / 8, 256, 0, stream>>>(er, rowptr, dinv, x, Mz, Mh, cz, ch,
                                        Wout, bout, out);
}

// Round 3
// 321.456 us; speedup vs baseline: 1.7658x; 1.7658x over previous
//
#include <hip/hip_runtime.h>

#define NN 50000
#define NE 1600000
#define PAD 16            // u32 stride per counter slot = 64B
#define TILE 250          // nodes per scan block; 200 * 250 = 50000 exactly
#define NBLK 200

// ---------------- workspace layout ----------------
// er[NE] float2           : {src_bits, dinv[src]*ew} grouped by dst   12.8 MB
// cnt_pad[NN*PAD] u32     : in-degree count, 1 slot / 64B line         3.2 MB  (memset)
// deg_pad[NN*PAD] f32     : in-weight sum,   1 slot / 64B line         3.2 MB  (memset)
// pos_pad[NN*PAD] u32     : scatter cursor                             3.2 MB
// dinv[NN], cnt_lin[NN], rowptr[NN+1], part[256], partoff[256]
// Mz[1024] Mh[1024] cz[32] ch[32]

// Fold Wz@Lzw[:32,:] -> Mz (cz = bz@Lzw + Lzb); same for h gate.
__global__ void k_prep(const float* __restrict__ Wz, const float* __restrict__ Lzw,
                       const float* __restrict__ bz, const float* __restrict__ Lzb,
                       const float* __restrict__ Wh, const float* __restrict__ Lhw,
                       const float* __restrict__ bh, const float* __restrict__ Lhb,
                       float* __restrict__ Mz, float* __restrict__ Mh,
                       float* __restrict__ cz, float* __restrict__ ch) {
    int t = threadIdx.x;
    int i = t >> 5, j = t & 31;
    float sz = 0.f, sh = 0.f;
#pragma unroll
    for (int k = 0; k < 32; ++k) {
        sz += Wz[i * 32 + k] * Lzw[k * 32 + j];
        sh += Wh[i * 32 + k] * Lhw[k * 32 + j];
    }
    Mz[i * 32 + j] = sz;
    Mh[i * 32 + j] = sh;
    if (t < 32) {
        float az = Lzb[t], ah = Lhb[t];
        for (int k = 0; k < 32; ++k) {
            az += bz[k] * Lzw[k * 32 + t];
            ah += bh[k] * Lhw[k * 32 + t];
        }
        cz[t] = az;
        ch[t] = ah;
    }
}

// Padded histograms: each node's counters live on a private 64B line.
__global__ void k_count(const int* __restrict__ ei, const float* __restrict__ ew,
                        unsigned* __restrict__ cnt_pad, float* __restrict__ deg_pad) {
    int e = blockIdx.x * blockDim.x + threadIdx.x;
    if (e < NE) {
        int d = ei[NE + e];
        atomicAdd(&cnt_pad[(unsigned)d * PAD], 1u);
        atomicAdd(&deg_pad[(unsigned)d * PAD], ew[e]);
    }
}

// Stage A: gather padded counters -> cnt_lin, per-block sums -> part[b]; dinv.
__global__ __launch_bounds__(256) void k_scanA(
        const unsigned* __restrict__ cnt_pad, const float* __restrict__ deg_pad,
        unsigned* __restrict__ cnt_lin, unsigned* __restrict__ part,
        float* __restrict__ dinv) {
    __shared__ unsigned red[256];
    int t = threadIdx.x;
    int n = blockIdx.x * TILE + t;
    unsigned v = 0;
    if (t < TILE) {
        v = cnt_pad[(unsigned)n * PAD];
        cnt_lin[n] = v;
        dinv[n] = rsqrtf(deg_pad[(unsigned)n * PAD] + 1.0f);  // +1 self-loop
    }
    red[t] = v;
    __syncthreads();
#pragma unroll
    for (int off = 128; off >= 1; off >>= 1) {
        if (t < off) red[t] += red[t + off];
        __syncthreads();
    }
    if (t == 0) part[blockIdx.x] = red[0];
}

// Stage B: 1-block exclusive scan of 200 partials -> partoff; rowptr[NN]=NE.
__global__ __launch_bounds__(256) void k_scanB(const unsigned* __restrict__ part,
                                               unsigned* __restrict__ partoff,
                                               unsigned* __restrict__ rowptr) {
    __shared__ unsigned s[256];
    int t = threadIdx.x;
    s[t] = (t < NBLK) ? part[t] : 0u;
    __syncthreads();
#pragma unroll
    for (int off = 1; off < 256; off <<= 1) {
        unsigned v = (t >= off) ? s[t - off] : 0u;
        __syncthreads();
        s[t] += v;
        __syncthreads();
    }
    if (t < NBLK) partoff[t] = (t > 0) ? s[t - 1] : 0u;
    if (t == 0) rowptr[NN] = NE;
}

// Stage C: block-local exclusive scan over TILE nodes -> rowptr & pos_pad init.
__global__ __launch_bounds__(256) void k_scanC(
        const unsigned* __restrict__ cnt_lin, const unsigned* __restrict__ partoff,
        unsigned* __restrict__ rowptr, unsigned* __restrict__ pos_pad) {
    __shared__ unsigned s[256];
    int t = threadIdx.x;
    int n = blockIdx.x * TILE + t;
    unsigned v = (t < TILE) ? cnt_lin[n] : 0u;
    s[t] = v;
    __syncthreads();
#pragma unroll
    for (int off = 1; off < 256; off <<= 1) {
        unsigned u = (t >= off) ? s[t - off] : 0u;
        __syncthreads();
        s[t] += u;
        __syncthreads();
    }
    if (t < TILE) {
        unsigned r = partoff[blockIdx.x] + s[t] - v;  // exclusive
        rowptr[n] = r;
        pos_pad[(unsigned)n * PAD] = r;
    }
}

// Place {src, dinv[src]*ew} at the dst row cursor (padded -> low line contention).
__global__ void k_scatter(const int* __restrict__ ei, const float* __restrict__ ew,
                          const float* __restrict__ dinv, unsigned* __restrict__ pos_pad,
                          float2* __restrict__ er) {
    int e = blockIdx.x * blockDim.x + threadIdx.x;
    if (e < NE) {
        int s = ei[e];
        int d = ei[NE + e];
        float v = dinv[s] * ew[e];
        unsigned idx = atomicAdd(&pos_pad[(unsigned)d * PAD], 1u);
        er[idx] = make_float2(__int_as_float(s), v);
    }
}

// Owner-computes gather + dense epilogue. 32 lanes = 1 node, 8 nodes/block.
__global__ __launch_bounds__(256) void k_fused(
        const float2* __restrict__ er, const unsigned* __restrict__ rowptr,
        const float* __restrict__ dinv, const float* __restrict__ x,
        const float* __restrict__ Mz, const float* __restrict__ Mh,
        const float* __restrict__ cz, const float* __restrict__ ch,
        const float* __restrict__ Wout, const float* __restrict__ bout,
        float* __restrict__ out) {
    __shared__ float sMz[1024], sMh[1024], sW[512], scz[32], sch[32], sb[16];
    __shared__ float sA[8][32];
    int tid = threadIdx.x;
    for (int i = tid; i < 1024; i += 256) { sMz[i] = Mz[i]; sMh[i] = Mh[i]; }
    for (int i = tid; i < 512; i += 256) sW[i] = Wout[i];
    if (tid < 32) { scz[tid] = cz[tid]; sch[tid] = ch[tid]; }
    if (tid < 16) sb[tid] = bout[tid];
    __syncthreads();

    int g = tid >> 5, f = tid & 31;
    int n = blockIdx.x * 8 + g;

    unsigned beg = rowptr[n], end = rowptr[n + 1];
    float t = 0.f;
    unsigned i = beg;
    // 4-wide unroll: batch the record loads, then the dependent x-row gathers.
    for (; i + 4 <= end; i += 4) {
        float2 r0 = er[i], r1 = er[i + 1], r2 = er[i + 2], r3 = er[i + 3];
        int s0 = __float_as_int(r0.x), s1 = __float_as_int(r1.x);
        int s2 = __float_as_int(r2.x), s3 = __float_as_int(r3.x);
        t += r0.y * x[s0 * 32 + f];
        t += r1.y * x[s1 * 32 + f];
        t += r2.y * x[s2 * 32 + f];
        t += r3.y * x[s3 * 32 + f];
    }
    for (; i < end; ++i) {
        float2 r = er[i];
        t += r.y * x[__float_as_int(r.x) * 32 + f];
    }
    float dn = dinv[n];
    float a = dn * (t + dn * x[n * 32 + f]);   // self-loop folded in
    sA[g][f] = a;
    __syncthreads();

    float z = scz[f], gh = sch[f];
#pragma unroll
    for (int k = 0; k < 32; ++k) {
        float ak = sA[g][k];
        z += ak * sMz[k * 32 + f];
        gh += ak * sMh[k * 32 + f];
    }
    z = 1.0f / (1.0f + expf(-z));
    gh = tanhf(gh);
    float hv = (1.0f - z) * gh;
    hv = hv > 0.f ? hv : 0.f;
    __syncthreads();
    sA[g][f] = hv;
    __syncthreads();

    if (f < 16) {
        float l = sb[f];
#pragma unroll
        for (int j = 0; j < 32; ++j) l += sA[g][j] * sW[j * 16 + f];
        float mx = l;
#pragma unroll
        for (int w = 8; w >= 1; w >>= 1) mx = fmaxf(mx, __shfl_xor(mx, w, 16));
        float p = expf(l - mx);
        float sum = p;
#pragma unroll
        for (int w = 8; w >= 1; w >>= 1) sum += __shfl_xor(sum, w, 16);
        out[n * 16 + f] = p / sum;
    }
}

extern "C" void kernel_launch(void* const* d_in, const int* in_sizes, int n_in,
                              void* d_out, int out_size, void* d_ws, size_t ws_size,
                              hipStream_t stream) {
    const float* x    = (const float*)d_in[0];
    const int*   ei   = (const int*)d_in[1];
    const float* ew   = (const float*)d_in[2];
    const float* Wz   = (const float*)d_in[3];
    const float* bz   = (const float*)d_in[4];
    // d_in[5..6] (Wr,br), d_in[11..12] (Lr): dead — R gate multiplies H0 = 0.
    const float* Wh   = (const float*)d_in[7];
    const float* bh   = (const float*)d_in[8];
    const float* Lzw  = (const float*)d_in[9];
    const float* Lzb  = (const float*)d_in[10];
    const float* Lhw  = (const float*)d_in[13];
    const float* Lhb  = (const float*)d_in[14];
    const float* Wout = (const float*)d_in[15];
    const float* bout = (const float*)d_in[16];
    float* out = (float*)d_out;

    float* ws = (float*)d_ws;
    float2*   er      = (float2*)ws;                         // NE float2
    unsigned* cnt_pad = (unsigned*)(ws + 2 * (size_t)NE);    // NN*PAD u32
    float*    deg_pad = (float*)(cnt_pad + (size_t)NN * PAD);// NN*PAD f32
    unsigned* pos_pad = (unsigned*)(deg_pad + (size_t)NN * PAD);
    float*    dinv    = (float*)(pos_pad + (size_t)NN * PAD);// NN
    unsigned* cnt_lin = (unsigned*)(dinv + NN);              // NN
    unsigned* rowptr  = cnt_lin + NN;                        // NN+1
    unsigned* part    = rowptr + NN + 1;                     // 256
    unsigned* partoff = part + 256;                          // 256
    float*    Mz      = (float*)(partoff + 256);             // 1024
    float*    Mh      = Mz + 1024;
    float*    cz      = Mh + 1024;
    float*    ch      = cz + 32;

    // zero only the accumulated histograms (cnt_pad + deg_pad, contiguous)
    hipMemsetAsync(cnt_pad, 0, 2 * (size_t)NN * PAD * sizeof(unsigned), stream);

    k_prep<<<1, 1024, 0, stream>>>(Wz, Lzw, bz, Lzb, Wh, Lhw, bh, Lhb, Mz, Mh, cz, ch);
    k_count<<<(NE + 255) / 256, 256, 0, stream>>>(ei, ew, cnt_pad, deg_pad);
    k_scanA<<<NBLK, 256, 0, stream>>>(cnt_pad, deg_pad, cnt_lin, part, dinv);
    k_scanB<<<1, 256, 0, stream>>>(part, partoff, rowptr);
    k_scanC<<<NBLK, 256, 0, stream>>>(cnt_lin, partoff, rowptr, pos_pad);
    k_scatter<<<(NE + 255) / 256, 256, 0, stream>>>(ei, ew, dinv, pos_pad, er);
    k_fused<<<NN / 8, 256, 0, stream>>>(er, rowptr, dinv, x, Mz, Mh, cz, ch,
                                        Wout, bout, out);
}